// Round 2
// baseline (274.417 us; speedup 1.0000x reference)
//
#include <hip/hip_runtime.h>

// Linear attention ("Transformers are RNNs") for N=8, L=S=8192, H=8, D=Dv=32, fp32.
// out[n,l,h,v] = (sum_d fQ[l,d] * KV[d,v]) / (sum_d fQ[l,d]*Ksum[d] + eps)
// KV[d,v] = sum_s fK[s,d]*V[s,v]; Ksum[d] = sum_s fK[s,d]; f(x)=elu(x)+1.
// The /S on V and *S on out cancel exactly (power-of-2 scaling).

#define L_Q 8192
#define S_K 8192
#define DIM 32
#define RS 256              // floats between consecutive s (or l) rows
#define EPSV 1e-6f
#define NPAIR 64
#define WSFLOATS (NPAIR * 1056)

__device__ __forceinline__ float fmap(float x) {
    return x > 0.0f ? x + 1.0f : __expf(x);
}

// ---------------------------------------------------------------------------
// Kernel A: per (n,h), KV[32][32] and Ksum[32], split over S into CHUNKS.
// Block = 4 waves. Each WAVE owns a private 8-row staging tile (K+V) in LDS:
// no __syncthreads in the main loop (in-order per-wave DS pipe gives
// write->read visibility), and next-iter global float4s are prefetched into
// registers so HBM latency hides under the 128 FMAs/lane/iter.
// Reduction buffers are overlaid (union) on the staging tiles.
// ---------------------------------------------------------------------------
#define CHUNKS 32
#define SROWS (S_K / CHUNKS)   // 256 rows per block
#define A_ITERS (SROWS / 32)   // 8 iters; each iter: 4 waves x 8 rows
#define SKP 36

union SmemA {
    struct { float K[4][8][SKP]; float V[4][8][SKP]; } st;  // 9216 B
    struct { float red[4][64][16]; float redk[4][32]; } rd; // 16896 B
};

__global__ __launch_bounds__(256, 5) void kv_kernel(const float* __restrict__ Kg,
                                                    const float* __restrict__ Vg,
                                                    float* __restrict__ ws)
{
    __shared__ SmemA sm;
    const int pair = blockIdx.y;          // n*8 + h
    const int n = pair >> 3, h = pair & 7;
    const int t = threadIdx.x;
    const int w = t >> 6;                 // wave 0..3
    const int l = t & 63;                 // lane
    const int g = l >> 4;                 // row-split 0..3 -> rows 2g, 2g+1
    const int i = l & 15;
    const int db = i >> 2;                // d in [db*8, db*8+8)
    const int vb = i & 3;                 // v in [vb*8, vb*8+8)

    const int srow = l >> 3;              // staged row 0..7 within wave tile
    const int scol = (l & 7) * 4;

    const size_t base = ((size_t)n * S_K + (size_t)blockIdx.x * SROWS) * RS
                      + (size_t)h * DIM;
    size_t gaddr = base + (size_t)(w * 8 + srow) * RS + scol;

    float acc[8][8];
    float ksum[8];
    #pragma unroll
    for (int a = 0; a < 8; ++a) {
        ksum[a] = 0.0f;
        #pragma unroll
        for (int b = 0; b < 8; ++b) acc[a][b] = 0.0f;
    }

    // prefetch iter 0
    float4 pK = *(const float4*)(Kg + gaddr);
    float4 pV = *(const float4*)(Vg + gaddr);

    float (*sK)[SKP] = sm.st.K[w];
    float (*sV)[SKP] = sm.st.V[w];

    for (int it = 0; it < A_ITERS; ++it) {
        float4 a = pK;
        a.x = fmap(a.x); a.y = fmap(a.y); a.z = fmap(a.z); a.w = fmap(a.w);
        *(float4*)(&sK[srow][scol]) = a;
        *(float4*)(&sV[srow][scol]) = pV;
        if (it + 1 < A_ITERS) {           // prefetch next iter while computing
            gaddr += (size_t)32 * RS;
            pK = *(const float4*)(Kg + gaddr);
            pV = *(const float4*)(Vg + gaddr);
        }
        #pragma unroll
        for (int rr = 0; rr < 2; ++rr) {
            const int r = 2 * g + rr;
            const float4 k0 = *(const float4*)&sK[r][db * 8];
            const float4 k1 = *(const float4*)&sK[r][db * 8 + 4];
            const float4 v0 = *(const float4*)&sV[r][vb * 8];
            const float4 v1 = *(const float4*)&sV[r][vb * 8 + 4];
            const float kk[8] = {k0.x,k0.y,k0.z,k0.w,k1.x,k1.y,k1.z,k1.w};
            const float vv[8] = {v0.x,v0.y,v0.z,v0.w,v1.x,v1.y,v1.z,v1.w};
            #pragma unroll
            for (int a2 = 0; a2 < 8; ++a2) {
                ksum[a2] += kk[a2];
                #pragma unroll
                for (int b2 = 0; b2 < 8; ++b2) acc[a2][b2] += kk[a2] * vv[b2];
            }
        }
    }

    // reduce over row-split g (lane bits 4,5)
    #pragma unroll
    for (int a = 0; a < 8; ++a) {
        #pragma unroll
        for (int b = 0; b < 8; ++b) {
            acc[a][b] += __shfl_xor(acc[a][b], 16);
            acc[a][b] += __shfl_xor(acc[a][b], 32);
        }
        ksum[a] += __shfl_xor(ksum[a], 16);
        ksum[a] += __shfl_xor(ksum[a], 32);
    }
    __syncthreads();                       // staging done everywhere: overlay safe
    if (l < 16) {
        #pragma unroll
        for (int a = 0; a < 8; ++a)
            #pragma unroll
            for (int b = 0; b < 8; ++b)
                sm.rd.red[w][a * 8 + b][i] = acc[a][b];
        if (vb == 0) {
            #pragma unroll
            for (int a = 0; a < 8; ++a) sm.rd.redk[w][db * 8 + a] = ksum[a];
        }
    }
    __syncthreads();
    float* KVp = ws + pair * 1056;
    #pragma unroll
    for (int p = t; p < 1024; p += 256) {
        const int kIdx = p >> 4, iIdx = p & 15;
        const float v = sm.rd.red[0][kIdx][iIdx] + sm.rd.red[1][kIdx][iIdx]
                      + sm.rd.red[2][kIdx][iIdx] + sm.rd.red[3][kIdx][iIdx];
        const int d  = ((iIdx >> 2) << 3) + (kIdx >> 3);
        const int vv = ((iIdx & 3) << 3) + (kIdx & 7);
        unsafeAtomicAdd(&KVp[d * DIM + vv], v);
    }
    if (t < 32) {
        const float v = sm.rd.redk[0][t] + sm.rd.redk[1][t]
                      + sm.rd.redk[2][t] + sm.rd.redk[3][t];
        unsafeAtomicAdd(&KVp[1024 + t], v);
    }
}

// ---------------------------------------------------------------------------
// Kernel B: out rows. Block = 4 waves, 128 rows/block. Q staged transposed
// via float4 global loads; each lane computes a 4-row x 4-col tile with
// conflict-free b128 LDS reads.
// ---------------------------------------------------------------------------
#define BROWS 128
#define TP 132

__global__ __launch_bounds__(256, 8) void out_kernel(const float* __restrict__ Q,
                                                     const float* __restrict__ ws,
                                                     float* __restrict__ out)
{
    __shared__ float sQt[DIM][TP];
    __shared__ float sKV[DIM][DIM];
    __shared__ float sKs[DIM];

    const int pair = blockIdx.y;
    const int n = pair >> 3, h = pair & 7;
    const int t = threadIdx.x;
    const int w = t >> 6, l = t & 63;
    const int vb = l & 7;              // v in [vb*4, vb*4+4)
    const int rb = l >> 3;             // rows w*32 + rb*4 .. +3

    const float* wp = ws + pair * 1056;
    for (int p = t; p < 1024; p += 256) (&sKV[0][0])[p] = wp[p];
    if (t < DIM) sKs[t] = wp[1024 + t];

    const size_t qbase = ((size_t)n * L_Q + (size_t)blockIdx.x * BROWS) * RS
                       + (size_t)h * DIM;

    // stage 128 rows transposed: thread t loads a contiguous half-row (64 B)
    {
        const int r = t >> 1;
        const int half = (t & 1) * 16;
        const float* qp = Q + qbase + (size_t)r * RS + half;
        #pragma unroll
        for (int j = 0; j < 4; ++j) {
            const float4 v = *(const float4*)(qp + j * 4);
            sQt[half + j * 4 + 0][r] = fmap(v.x);
            sQt[half + j * 4 + 1][r] = fmap(v.y);
            sQt[half + j * 4 + 2][r] = fmap(v.z);
            sQt[half + j * 4 + 3][r] = fmap(v.w);
        }
    }
    __syncthreads();

    const int rowbase = w * 32 + rb * 4;
    float acc[4][4];
    float den[4] = {0.0f, 0.0f, 0.0f, 0.0f};
    #pragma unroll
    for (int j = 0; j < 4; ++j)
        #pragma unroll
        for (int b = 0; b < 4; ++b) acc[j][b] = 0.0f;

    #pragma unroll
    for (int d = 0; d < DIM; ++d) {
        const float4 q4 = *(const float4*)&sQt[d][rowbase];
        const float ksd = sKs[d];
        const float4 c = *(const float4*)&sKV[d][vb * 4];
        const float qq[4] = {q4.x, q4.y, q4.z, q4.w};
        const float cc[4] = {c.x, c.y, c.z, c.w};
        #pragma unroll
        for (int j = 0; j < 4; ++j) {
            den[j] += qq[j] * ksd;
            #pragma unroll
            for (int b = 0; b < 4; ++b) acc[j][b] += qq[j] * cc[b];
        }
    }

    #pragma unroll
    for (int j = 0; j < 4; ++j) {
        const float z = 1.0f / (den[j] + EPSV);
        float4 o;
        o.x = acc[j][0] * z; o.y = acc[j][1] * z;
        o.z = acc[j][2] * z; o.w = acc[j][3] * z;
        *(float4*)(out + qbase + (size_t)(rowbase + j) * RS + vb * 4) = o;
    }
}

extern "C" void kernel_launch(void* const* d_in, const int* in_sizes, int n_in,
                              void* d_out, int out_size, void* d_ws, size_t ws_size,
                              hipStream_t stream)
{
    const float* Q = (const float*)d_in[0];
    const float* K = (const float*)d_in[1];
    const float* V = (const float*)d_in[2];
    float* outp = (float*)d_out;
    float* ws = (float*)d_ws;

    // atomics accumulate into ws -> zero it every launch (ws is re-poisoned)
    hipMemsetAsync(d_ws, 0, WSFLOATS * sizeof(float), stream);

    dim3 gA(CHUNKS, NPAIR);
    kv_kernel<<<gA, 256, 0, stream>>>(K, V, ws);

    dim3 gB(L_Q / BROWS, NPAIR);
    out_kernel<<<gB, 256, 0, stream>>>(Q, ws, outp);
}

// Round 4
// 251.103 us; speedup vs baseline: 1.0928x; 1.0928x over previous
//
#include <hip/hip_runtime.h>

// Linear attention ("Transformers are RNNs") for N=8, L=S=8192, H=8, D=Dv=32, fp32.
// out[n,l,h,v] = (sum_d fQ[l,d] * KV[d,v]) / (sum_d fQ[l,d]*Ksum[d] + eps)
// KV[d,v] = sum_s fK[s,d]*V[s,v]; Ksum[d] = sum_s fK[s,d]; f(x)=elu(x)+1.
// The /S on V and *S on out cancel exactly (power-of-2 scaling).

#define L_Q 8192
#define S_K 8192
#define DIM 32
#define RS 256              // floats between consecutive s (or l) rows
#define EPSV 1e-6f
#define NPAIR 64
#define WSFLOATS (NPAIR * 1056)

__device__ __forceinline__ float fmap(float x) {
    return x > 0.0f ? x + 1.0f : __expf(x);
}

// ---------------------------------------------------------------------------
// Kernel A: per (n,h), KV[32][32] and Ksum[32], split over S into CHUNKS.
// Block = 4 waves. Each WAVE owns a private 8-row staging tile (K+V) in LDS:
// no __syncthreads in the main loop (in-order per-wave DS pipe gives
// write->read visibility). 1-deep register prefetch of next iter's globals.
// Per-lane tile is 4d x 8v (32 acc VGPRs): 64 lanes = 2x coverage of the
// 1024 KV outputs, rows split by lane bit 5 -> single shfl_xor(32) reduce.
// NO launch_bounds min-occupancy (round-2 spill lesson: VGPR cap -> scratch).
// ---------------------------------------------------------------------------
#define CHUNKS 64
#define SROWS (S_K / CHUNKS)   // 128 rows per block
#define A_ITERS (SROWS / 32)   // 4 iters; each iter: 4 waves x 8 rows
#define SKP 36

union SmemA {
    struct { float K[4][8][SKP]; float V[4][8][SKP]; } st;   // 9216 B
    struct { float red[4][32][36]; float redk[4][32]; } rd;  // 18944 B
};

__global__ __launch_bounds__(256) void kv_kernel(const float* __restrict__ Kg,
                                                 const float* __restrict__ Vg,
                                                 float* __restrict__ ws)
{
    __shared__ SmemA sm;
    const int pair = blockIdx.y;          // n*8 + h
    const int n = pair >> 3, h = pair & 7;
    const int t = threadIdx.x;
    const int w = t >> 6;                 // wave 0..3
    const int l = t & 63;                 // lane
    const int rsp = l >> 5;               // row-split: rows [rsp*4, rsp*4+4)
    const int q = l & 31;
    const int d0 = (q >> 2) * 4;          // d tile origin (4 wide)
    const int v0 = (q & 3) * 8;           // v tile origin (8 wide)

    const int srow = l >> 3;              // staged row 0..7 within wave tile
    const int scol = (l & 7) * 4;

    const size_t base = ((size_t)n * S_K + (size_t)blockIdx.x * SROWS) * RS
                      + (size_t)h * DIM;
    size_t gaddr = base + (size_t)(w * 8 + srow) * RS + scol;

    float acc[4][8];
    float ksum[4];
    #pragma unroll
    for (int a = 0; a < 4; ++a) {
        ksum[a] = 0.0f;
        #pragma unroll
        for (int b = 0; b < 8; ++b) acc[a][b] = 0.0f;
    }

    // prefetch iter 0
    float4 pK = *(const float4*)(Kg + gaddr);
    float4 pV = *(const float4*)(Vg + gaddr);

    float (*sK)[SKP] = sm.st.K[w];
    float (*sV)[SKP] = sm.st.V[w];

    for (int it = 0; it < A_ITERS; ++it) {
        float4 a = pK;
        a.x = fmap(a.x); a.y = fmap(a.y); a.z = fmap(a.z); a.w = fmap(a.w);
        *(float4*)(&sK[srow][scol]) = a;
        *(float4*)(&sV[srow][scol]) = pV;
        if (it + 1 < A_ITERS) {           // prefetch next iter while computing
            gaddr += (size_t)32 * RS;
            pK = *(const float4*)(Kg + gaddr);
            pV = *(const float4*)(Vg + gaddr);
        }
        #pragma unroll
        for (int rr = 0; rr < 4; ++rr) {
            const int r = rsp * 4 + rr;
            const float4 k4 = *(const float4*)&sK[r][d0];
            const float4 va = *(const float4*)&sV[r][v0];
            const float4 vb4 = *(const float4*)&sV[r][v0 + 4];
            const float kk[4] = {k4.x, k4.y, k4.z, k4.w};
            const float vv[8] = {va.x, va.y, va.z, va.w, vb4.x, vb4.y, vb4.z, vb4.w};
            #pragma unroll
            for (int a2 = 0; a2 < 4; ++a2) {
                ksum[a2] += kk[a2];
                #pragma unroll
                for (int b2 = 0; b2 < 8; ++b2) acc[a2][b2] += kk[a2] * vv[b2];
            }
        }
    }

    // reduce over row-split (lane bit 5)
    #pragma unroll
    for (int a = 0; a < 4; ++a) {
        ksum[a] += __shfl_xor(ksum[a], 32);
        #pragma unroll
        for (int b = 0; b < 8; ++b) acc[a][b] += __shfl_xor(acc[a][b], 32);
    }
    __syncthreads();                       // staging done everywhere: overlay safe
    if (l < 32) {
        #pragma unroll
        for (int a = 0; a < 4; ++a)
            #pragma unroll
            for (int b = 0; b < 8; ++b)
                sm.rd.red[w][q][a * 8 + b] = acc[a][b];
        if ((q & 3) == 0) {               // vb==0 lanes own ksum; q = db*4 so q+a = d
            #pragma unroll
            for (int a = 0; a < 4; ++a) sm.rd.redk[w][q + a] = ksum[a];
        }
    }
    __syncthreads();
    // cross-wave sum + atomics (each thread: one float4 worth of KV)
    float* KVp = ws + pair * 1056;
    {
        const int d = t >> 3;              // 0..31
        const int v = (t & 7) * 4;         // 0,4,...,28
        const int lq = (d >> 2) * 4 + (v >> 3);
        const int idx = (d & 3) * 8 + (v & 7);   // multiple of 4 -> aligned float4
        const float4 s0 = *(const float4*)&sm.rd.red[0][lq][idx];
        const float4 s1 = *(const float4*)&sm.rd.red[1][lq][idx];
        const float4 s2 = *(const float4*)&sm.rd.red[2][lq][idx];
        const float4 s3 = *(const float4*)&sm.rd.red[3][lq][idx];
        unsafeAtomicAdd(&KVp[d * DIM + v + 0], s0.x + s1.x + s2.x + s3.x);
        unsafeAtomicAdd(&KVp[d * DIM + v + 1], s0.y + s1.y + s2.y + s3.y);
        unsafeAtomicAdd(&KVp[d * DIM + v + 2], s0.z + s1.z + s2.z + s3.z);
        unsafeAtomicAdd(&KVp[d * DIM + v + 3], s0.w + s1.w + s2.w + s3.w);
    }
    if (t < 32) {
        const float s = sm.rd.redk[0][t] + sm.rd.redk[1][t]
                      + sm.rd.redk[2][t] + sm.rd.redk[3][t];
        unsafeAtomicAdd(&KVp[1024 + t], s);
    }
}

// ---------------------------------------------------------------------------
// Kernel B: out rows. Block = 4 waves, 128 rows/block. Q staged transposed
// via float4 global loads; each lane computes a 4-row x 4-col tile with
// conflict-free b128 LDS reads. No launch_bounds min-occupancy.
// ---------------------------------------------------------------------------
#define BROWS 128
#define TP 132

__global__ __launch_bounds__(256) void out_kernel(const float* __restrict__ Q,
                                                  const float* __restrict__ ws,
                                                  float* __restrict__ out)
{
    __shared__ float sQt[DIM][TP];
    __shared__ float sKV[DIM][DIM];
    __shared__ float sKs[DIM];

    const int pair = blockIdx.y;
    const int n = pair >> 3, h = pair & 7;
    const int t = threadIdx.x;
    const int w = t >> 6, l = t & 63;
    const int vb = l & 7;              // v in [vb*4, vb*4+4)
    const int rb = l >> 3;             // rows w*32 + rb*4 .. +3

    const float* wp = ws + pair * 1056;
    for (int p = t; p < 1024; p += 256) (&sKV[0][0])[p] = wp[p];
    if (t < DIM) sKs[t] = wp[1024 + t];

    const size_t qbase = ((size_t)n * L_Q + (size_t)blockIdx.x * BROWS) * RS
                       + (size_t)h * DIM;

    // stage 128 rows transposed: thread t loads a contiguous half-row (64 B)
    {
        const int r = t >> 1;
        const int half = (t & 1) * 16;
        const float* qp = Q + qbase + (size_t)r * RS + half;
        #pragma unroll
        for (int j = 0; j < 4; ++j) {
            const float4 v = *(const float4*)(qp + j * 4);
            sQt[half + j * 4 + 0][r] = fmap(v.x);
            sQt[half + j * 4 + 1][r] = fmap(v.y);
            sQt[half + j * 4 + 2][r] = fmap(v.z);
            sQt[half + j * 4 + 3][r] = fmap(v.w);
        }
    }
    __syncthreads();

    const int rowbase = w * 32 + rb * 4;
    float acc[4][4];
    float den[4] = {0.0f, 0.0f, 0.0f, 0.0f};
    #pragma unroll
    for (int j = 0; j < 4; ++j)
        #pragma unroll
        for (int b = 0; b < 4; ++b) acc[j][b] = 0.0f;

    #pragma unroll
    for (int d = 0; d < DIM; ++d) {
        const float4 q4 = *(const float4*)&sQt[d][rowbase];
        const float ksd = sKs[d];
        const float4 c = *(const float4*)&sKV[d][vb * 4];
        const float qq[4] = {q4.x, q4.y, q4.z, q4.w};
        const float cc[4] = {c.x, c.y, c.z, c.w};
        #pragma unroll
        for (int j = 0; j < 4; ++j) {
            den[j] += qq[j] * ksd;
            #pragma unroll
            for (int b = 0; b < 4; ++b) acc[j][b] += qq[j] * cc[b];
        }
    }

    #pragma unroll
    for (int j = 0; j < 4; ++j) {
        const float z = 1.0f / (den[j] + EPSV);
        float4 o;
        o.x = acc[j][0] * z; o.y = acc[j][1] * z;
        o.z = acc[j][2] * z; o.w = acc[j][3] * z;
        *(float4*)(out + qbase + (size_t)(rowbase + j) * RS + vb * 4) = o;
    }
}

extern "C" void kernel_launch(void* const* d_in, const int* in_sizes, int n_in,
                              void* d_out, int out_size, void* d_ws, size_t ws_size,
                              hipStream_t stream)
{
    const float* Q = (const float*)d_in[0];
    const float* K = (const float*)d_in[1];
    const float* V = (const float*)d_in[2];
    float* outp = (float*)d_out;
    float* ws = (float*)d_ws;

    // atomics accumulate into ws -> zero it every launch (ws is re-poisoned)
    hipMemsetAsync(d_ws, 0, WSFLOATS * sizeof(float), stream);

    dim3 gA(CHUNKS, NPAIR);
    kv_kernel<<<gA, 256, 0, stream>>>(K, V, ws);

    dim3 gB(L_Q / BROWS, NPAIR);
    out_kernel<<<gB, 256, 0, stream>>>(Q, ws, outp);
}

// Round 9
// 238.960 us; speedup vs baseline: 1.1484x; 1.0508x over previous
//
#include <hip/hip_runtime.h>

// Linear attention, N=8, L=S=8192, H=8, D=Dv=32, fp32.
// out[n,l,h,v] = (sum_d fQ[l,d] * KV[h][d,v]) / (sum_d fQ[l,d]*Ksum[h][d] + eps)
// KV = sum_s fK V^T per (n,h); f(x)=elu(x)+1. /S and *S cancel exactly.
//
// Round-5 design: contiguous all-head tiles (perfect float4 coalescing),
// deterministic partials in ws (NO atomics - round-4 lesson: 4.3M write-through
// atomics = 66MB HBM writes + contention), tiny reduce kernel, LDS pitch 268
// floats (67 float4) chosen so every access pattern spreads evenly over the
// 8 16B-bank-groups (mod-8 balanced).

#define RS4 64              // 256 floats per (n,row) = 64 float4
#define EPSV 1e-6f

#define KV_CH 32            // S-chunks
#define KV_ROWS 256         // rows per kv block
#define KV_TILE 16          // rows per kv iter
#define KV_ITERS 16
#define PH4 264             // 1056 floats per (pair,chunk) partial, in float4
#define FIN4 (8 * KV_CH * 8 * PH4)   // float4 offset of final KV region (8.65MB)

#define KP 67               // kv LDS row pitch (float4)
#define OP 67               // out sQ pitch (float4)
#define KVP 265             // out sKV per-head pitch (float4) = 1060 floats

__device__ __forceinline__ float fmap(float x) {
    return x > 0.0f ? x + 1.0f : __expf(x);
}
__device__ __forceinline__ float4 fmap4(float4 v) {
    return make_float4(fmap(v.x), fmap(v.y), fmap(v.z), fmap(v.w));
}
__device__ __forceinline__ float f4c(const float4& v, int i) {
    return i == 0 ? v.x : i == 1 ? v.y : i == 2 ? v.z : v.w;
}

// ---------------------------------------------------------------------------
// Kernel A: block (c, n) accumulates KV[8 heads][32x32] + Ksum over 256 rows.
// All global loads: lane-consecutive float4 over contiguous 16KB tiles.
// 256 threads = 8 head-groups x 32 lanes; lane owns 8d x 4v (acc[8][4]),
// sees ALL rows -> no cross-lane reduction. Double-buffered LDS, 1 sync/iter,
// depth-1 register prefetch. Partials stored deterministically to ws.
// ---------------------------------------------------------------------------
__global__ __launch_bounds__(256) void kv_kernel(const float4* __restrict__ Kg,
                                                 const float4* __restrict__ Vg,
                                                 float4* __restrict__ ws)
{
    __shared__ float4 sK[2][KV_TILE * KP];   // 2 x 17.15KB
    __shared__ float4 sV[2][KV_TILE * KP];

    const int n = blockIdx.y, c = blockIdx.x;
    const int t = threadIdx.x;
    const int h = t >> 5;            // head 0..7
    const int q = t & 31;
    const int dq = (q >> 3) * 2;     // d0/4, d0 = (q>>3)*8
    const int vs = q & 7;            // v0/4, v0 = vs*4

    size_t gbase = ((size_t)n * 8192 + (size_t)c * KV_ROWS) * RS4 + t;

    float acc[8][4];
    float ksum[8];
    #pragma unroll
    for (int a = 0; a < 8; ++a) {
        ksum[a] = 0.0f;
        acc[a][0] = acc[a][1] = acc[a][2] = acc[a][3] = 0.0f;
    }

    float4 pK[4], pV[4];
    #pragma unroll
    for (int k = 0; k < 4; ++k) { pK[k] = Kg[gbase + k * 256]; pV[k] = Vg[gbase + k * 256]; }

    for (int it = 0; it < KV_ITERS; ++it) {
        float4* bK = sK[it & 1];
        float4* bV = sV[it & 1];
        #pragma unroll
        for (int k = 0; k < 4; ++k) {
            const int idx = k * 256 + t;                 // float4 idx in 16-row tile
            const int dst = (idx >> 6) * KP + (idx & 63);
            bK[dst] = fmap4(pK[k]);
            bV[dst] = pV[k];
        }
        if (it + 1 < KV_ITERS) {
            gbase += (size_t)KV_TILE * RS4;              // +1024 float4
            #pragma unroll
            for (int k = 0; k < 4; ++k) { pK[k] = Kg[gbase + k * 256]; pV[k] = Vg[gbase + k * 256]; }
        }
        __syncthreads();   // double-buffer: one sync/iter is sufficient
        #pragma unroll
        for (int r = 0; r < KV_TILE; ++r) {
            const float4 k0 = bK[r * KP + h * 8 + dq];
            const float4 k1 = bK[r * KP + h * 8 + dq + 1];
            const float4 v  = bV[r * KP + h * 8 + vs];
            const float kk[8] = {k0.x, k0.y, k0.z, k0.w, k1.x, k1.y, k1.z, k1.w};
            #pragma unroll
            for (int a = 0; a < 8; ++a) {
                ksum[a]   += kk[a];
                acc[a][0] += kk[a] * v.x;
                acc[a][1] += kk[a] * v.y;
                acc[a][2] += kk[a] * v.z;
                acc[a][3] += kk[a] * v.w;
            }
        }
    }

    // deterministic partial store (coalesced float4, ~8.7MB total)
    const size_t pb = ((size_t)(n * KV_CH + c) * 8 + h) * PH4;
    const int d0 = (q >> 3) * 8;
    #pragma unroll
    for (int a = 0; a < 8; ++a)
        ws[pb + (size_t)(d0 + a) * 8 + vs] =
            make_float4(acc[a][0], acc[a][1], acc[a][2], acc[a][3]);
    if (vs == 0) {   // Ksum at float offset 1024+d -> float4 idx 256 + d/4
        ws[pb + 256 + dq]     = make_float4(ksum[0], ksum[1], ksum[2], ksum[3]);
        ws[pb + 256 + dq + 1] = make_float4(ksum[4], ksum[5], ksum[6], ksum[7]);
    }
}

// ---------------------------------------------------------------------------
// Reduce: 64 blocks (one per pair), sum 32 chunk-partials -> final region.
// ---------------------------------------------------------------------------
__global__ __launch_bounds__(256) void reduce_kernel(float4* __restrict__ ws)
{
    const int pair = blockIdx.x;          // n*8 + h
    const int n = pair >> 3, h = pair & 7;
    const int t = threadIdx.x;
    const size_t cs = 8 * PH4;            // chunk stride (float4)

    for (int e = t; e < PH4; e += 256) {
        const size_t b = ((size_t)(n * KV_CH) * 8 + h) * PH4 + e;
        float4 s0 = make_float4(0.f, 0.f, 0.f, 0.f), s1 = s0, s2 = s0, s3 = s0;
        #pragma unroll
        for (int c = 0; c < KV_CH; c += 4) {
            const float4 a0 = ws[b + (size_t)(c + 0) * cs];
            const float4 a1 = ws[b + (size_t)(c + 1) * cs];
            const float4 a2 = ws[b + (size_t)(c + 2) * cs];
            const float4 a3 = ws[b + (size_t)(c + 3) * cs];
            s0.x += a0.x; s0.y += a0.y; s0.z += a0.z; s0.w += a0.w;
            s1.x += a1.x; s1.y += a1.y; s1.z += a1.z; s1.w += a1.w;
            s2.x += a2.x; s2.y += a2.y; s2.z += a2.z; s2.w += a2.w;
            s3.x += a3.x; s3.y += a3.y; s3.z += a3.z; s3.w += a3.w;
        }
        ws[FIN4 + (size_t)pair * PH4 + e] =
            make_float4(s0.x + s1.x + s2.x + s3.x, s0.y + s1.y + s2.y + s3.y,
                        s0.z + s1.z + s2.z + s3.z, s0.w + s1.w + s2.w + s3.w);
    }
}

// ---------------------------------------------------------------------------
// Kernel B: block (cL, n): 128 rows x all 8 heads. KV for all heads in LDS
// (34KB); 32-row Q tiles staged contiguously with fmap; lane = 8 rows x 4 v.
// All global reads AND writes fully lane-consecutive.
// ---------------------------------------------------------------------------
__global__ __launch_bounds__(256) void out_kernel(const float4* __restrict__ Q,
                                                  const float4* __restrict__ ws,
                                                  float4* __restrict__ out)
{
    __shared__ float4 sKV[8 * KVP];      // 33.9KB
    __shared__ float4 sQ[32 * OP];       // 34.3KB

    const int n = blockIdx.y, cL = blockIdx.x;
    const int t = threadIdx.x;
    const int h = t >> 5;
    const int q = t & 31;
    const int rblk = q >> 3;             // 0..3 ; lane rows = rblk + 4j
    const int vs = q & 7;                // v float4 slice

    size_t gbase = ((size_t)n * 8192 + (size_t)cL * 128) * RS4 + t;

    // prefetch Q tile 0 (in flight during KV load)
    float4 pf[8];
    #pragma unroll
    for (int k = 0; k < 8; ++k) pf[k] = Q[gbase + k * 256];

    // load final KV (8 heads x 1056 floats) into LDS
    {
        const size_t fb = FIN4 + (size_t)n * 8 * PH4;
        #pragma unroll
        for (int k = 0; k < 9; ++k) {
            const int p = k * 256 + t;
            if (p < 8 * PH4) {
                const int hh = p / PH4, e = p - hh * PH4;
                sKV[hh * KVP + e] = ws[fb + p];
            }
        }
    }

    for (int it = 0; it < 4; ++it) {
        __syncthreads();     // previous compute done -> safe to overwrite sQ
        #pragma unroll
        for (int k = 0; k < 8; ++k) {
            const int idx = k * 256 + t;                  // float4 idx in 32-row tile
            sQ[(idx >> 6) * OP + (idx & 63)] = fmap4(pf[k]);
        }
        if (it + 1 < 4) {
            gbase += (size_t)32 * RS4;                    // +2048 float4
            #pragma unroll
            for (int k = 0; k < 8; ++k) pf[k] = Q[gbase + k * 256];
        }
        __syncthreads();     // sQ (and, at it=0, sKV) visible

        float acc[8][4];
        float den[8];
        #pragma unroll
        for (int j = 0; j < 8; ++j) {
            den[j] = 0.0f;
            acc[j][0] = acc[j][1] = acc[j][2] = acc[j][3] = 0.0f;
        }

        #pragma unroll
        for (int dc = 0; dc < 8; ++dc) {
            const float4 ks = sKV[h * KVP + 256 + dc];
            float4 qr[8];
            #pragma unroll
            for (int j = 0; j < 8; ++j)
                qr[j] = sQ[(rblk + 4 * j) * OP + h * 8 + dc];
            #pragma unroll
            for (int dd = 0; dd < 4; ++dd) {
                const float4 kv = sKV[h * KVP + (dc * 4 + dd) * 8 + vs];
                const float ksd = f4c(ks, dd);
                #pragma unroll
                for (int j = 0; j < 8; ++j) {
                    const float qv = f4c(qr[j], dd);
                    acc[j][0] += qv * kv.x;
                    acc[j][1] += qv * kv.y;
                    acc[j][2] += qv * kv.z;
                    acc[j][3] += qv * kv.w;
                    den[j]    += qv * ksd;
                }
            }
        }

        const size_t ob = ((size_t)n * 8192 + (size_t)cL * 128 + it * 32 + rblk) * RS4
                        + h * 8 + vs;
        #pragma unroll
        for (int j = 0; j < 8; ++j) {
            const float z = 1.0f / (den[j] + EPSV);
            out[ob + (size_t)(4 * j) * RS4] =
                make_float4(acc[j][0] * z, acc[j][1] * z, acc[j][2] * z, acc[j][3] * z);
        }
    }
}

extern "C" void kernel_launch(void* const* d_in, const int* in_sizes, int n_in,
                              void* d_out, int out_size, void* d_ws, size_t ws_size,
                              hipStream_t stream)
{
    const float4* Q = (const float4*)d_in[0];
    const float4* K = (const float4*)d_in[1];
    const float4* V = (const float4*)d_in[2];
    float4* outp = (float4*)d_out;
    float4* ws = (float4*)d_ws;

    // no memset needed: partials + final are fully overwritten each launch

    dim3 gA(KV_CH, 8);
    kv_kernel<<<gA, 256, 0, stream>>>(K, V, ws);

    reduce_kernel<<<64, 256, 0, stream>>>(ws);

    dim3 gB(64, 8);
    out_kernel<<<gB, 256, 0, stream>>>(Q, ws, outp);
}